// Round 7
// baseline (151.341 us; speedup 1.0000x reference)
//
#include <hip/hip_runtime.h>
#include <stdint.h>

// Problem dims (fixed by reference): E=16, B=8, S=2048, D=2048
#define N_TOK   16384          // B*S
#define D_MODEL 2048
#define N_EXP   16
#define CAP     1024           // N_TOK / N_EXP
#define TOTAL   (N_TOK * D_MODEL)        // 33,554,432 elements

#define BLK_TOK 8              // token rows per block
#define THREADS 256
#define STEPS   16             // float4 groups per thread
#define NBLK    (N_TOK / BLK_TOK)        // 2048 blocks
#define PF      2              // prefetch distance (steps)

// keep  <=>  u < 0.9f  <=>  bits < 7549747<<9  (0.9f == 7549747*2^-23 exactly)
#define KEEP_THR_SH 0xE6666600u

// ---------------------------------------------------------------------------
// rotl forced to a single v_alignbit_b32: rotl(x,r) == {x,x} >> (32-r).
// ---------------------------------------------------------------------------
template <int R>
__device__ __forceinline__ uint32_t rotl(uint32_t x) {
    uint32_t d;
    asm("v_alignbit_b32 %0, %1, %1, %2" : "=v"(d) : "v"(x), "n"(32 - R));
    return d;
}

// ---------------------------------------------------------------------------
// Threefry-2x32, 20 rounds, key = (0, 42) == jax.random.key(42).
// Partitionable path: counter = (0, i); 32-bit draw = XOR-fold x0 ^ x1.
// ---------------------------------------------------------------------------
__device__ __forceinline__ uint32_t tf_bits(uint32_t i) {
    const uint32_t k0 = 0u;
    const uint32_t k1 = 42u;
    const uint32_t k2 = 0x1BD11BDAu ^ 0u ^ 42u;
    uint32_t x0 = 0u + k0;        // counter hi = 0
    uint32_t x1 = i + k1;         // counter lo = i
#define TF_R(r) { x0 += x1; x1 = rotl<r>(x1) ^ x0; }
    TF_R(13) TF_R(15) TF_R(26) TF_R(6)
    x0 += k1; x1 += k2 + 1u;
    TF_R(17) TF_R(29) TF_R(16) TF_R(24)
    x0 += k2; x1 += k0 + 2u;
    TF_R(13) TF_R(15) TF_R(26) TF_R(6)
    x0 += k0; x1 += k1 + 3u;
    TF_R(17) TF_R(29) TF_R(16) TF_R(24)
    x0 += k1; x1 += k2 + 4u;
    TF_R(13) TF_R(15) TF_R(26) TF_R(6)
    x0 += k2; x1 += k0 + 5u;
#undef TF_R
    return x0 ^ x1;               // XOR-fold (partitionable sub-64 narrowing)
}

// ---------------------------------------------------------------------------
// Kernel 1: within-expert rank. srcrow[t] = routes[t]*CAP + rank(t)
// ---------------------------------------------------------------------------
__global__ __launch_bounds__(64) void rank_kernel(const int* __restrict__ routes,
                                                  int* __restrict__ srcrow) {
    const int e    = blockIdx.x;     // expert id
    const int lane = threadIdx.x;    // 0..63
    const int4* routes4 = (const int4*)routes;
    int running = 0;
    for (int base = 0; base < N_TOK / 4; base += 64) {
        int4 r = routes4[base + lane];
        int m0 = (r.x == e), m1 = (r.y == e), m2 = (r.z == e), m3 = (r.w == e);
        int cnt = m0 + m1 + m2 + m3;
        int pre = cnt;
        #pragma unroll
        for (int dlt = 1; dlt < 64; dlt <<= 1) {
            int up = __shfl_up(pre, dlt);
            if (lane >= dlt) pre += up;
        }
        int excl = pre - cnt;
        int tot  = __shfl(pre, 63);
        int t0 = (base + lane) * 4;
        int p = running + excl;
        if (m0) { srcrow[t0 + 0] = e * CAP + p; p++; }
        if (m1) { srcrow[t0 + 1] = e * CAP + p; p++; }
        if (m2) { srcrow[t0 + 2] = e * CAP + p; p++; }
        if (m3) { srcrow[t0 + 3] = e * CAP + p; p++; }
        running += tot;
    }
}

// ---------------------------------------------------------------------------
// Kernel 2: combine + dropout + residual, explicitly pinned 2-deep pipeline.
// Block = 8 token rows, 256 threads, 16 float4 steps/thread (static unroll).
// Loads for step k+2 issue BEFORE threefry of step k; sched_barrier(0) stops
// the scheduler from sinking them; the waitcnt pass then emits counted vmcnt
// (4 loads + stores outstanding) before each consume.
// __launch_bounds__(256,4): allow 128 VGPR so the pipeline regs can live.
// ---------------------------------------------------------------------------
__global__ __launch_bounds__(THREADS, 4) void combine_kernel(
        const float4* __restrict__ hidden,
        const float4* __restrict__ eo4,
        const int*    __restrict__ srcrow,
        const float*  __restrict__ rpm,
        float4*       __restrict__ out) {
    const int b     = blockIdx.x;
    const int tid   = threadIdx.x;                 // 0..255
    const int t0    = b * BLK_TOK;
    const int gbase = b * (BLK_TOK * 512);         // first float4 of block

    // Block-uniform per-row scalars (scalarize to SGPRs; readonly+uniform)
    int   r[BLK_TOK];
    float sc[BLK_TOK];
    #pragma unroll
    for (int q = 0; q < BLK_TOK; ++q) {
        r[q]  = srcrow[t0 + q];
        sc[q] = rpm[t0 + q] * (1.0f / 0.9f);
    }

    // Pipeline buffers — all indices compile-time (full unroll), so regalloc
    // sees short 2-3 step live ranges, not STEPS*8 registers.
    float4 hb[STEPS], eb[STEPS];

    // Prologue: fill PF steps
    #pragma unroll
    for (int k = 0; k < PF; ++k) {
        const int idx = k * THREADS + tid;
        hb[k] = hidden[gbase + idx];
        eb[k] = eo4[(r[k >> 1] << 9) + (idx & 511)];
    }
    __builtin_amdgcn_sched_barrier(0);

    #pragma unroll
    for (int k = 0; k < STEPS; ++k) {
        // 1) issue step k+PF loads
        if (k + PF < STEPS) {
            const int idx = (k + PF) * THREADS + tid;
            hb[k + PF] = hidden[gbase + idx];
            eb[k + PF] = eo4[(r[(k + PF) >> 1] << 9) + (idx & 511)];
        }
        // 2) pin: loads above may not sink past this point
        __builtin_amdgcn_sched_barrier(0);

        // 3) threefry burst (no memory deps)
        const uint32_t j = (uint32_t)(gbase + k * THREADS + tid) << 2;
        const uint32_t b0 = tf_bits(j + 0);
        const uint32_t b1 = tf_bits(j + 1);
        const uint32_t b2 = tf_bits(j + 2);
        const uint32_t b3 = tf_bits(j + 3);

        // 4) consume step k (auto counted-vmcnt wait lands here)
        const float s  = sc[k >> 1];
        const float m0 = (b0 < KEEP_THR_SH) ? s : 0.0f;
        const float m1 = (b1 < KEEP_THR_SH) ? s : 0.0f;
        const float m2 = (b2 < KEEP_THR_SH) ? s : 0.0f;
        const float m3 = (b3 < KEEP_THR_SH) ? s : 0.0f;

        float4 o;
        o.x = fmaf(m0, eb[k].x, hb[k].x);
        o.y = fmaf(m1, eb[k].y, hb[k].y);
        o.z = fmaf(m2, eb[k].z, hb[k].z);
        o.w = fmaf(m3, eb[k].w, hb[k].w);
        out[gbase + k * THREADS + tid] = o;
    }
}

// ---------------------------------------------------------------------------
extern "C" void kernel_launch(void* const* d_in, const int* in_sizes, int n_in,
                              void* d_out, int out_size, void* d_ws, size_t ws_size,
                              hipStream_t stream) {
    const float* hidden = (const float*)d_in[0];   // [B,S,D] f32
    const float* eo     = (const float*)d_in[1];   // [E,CAP,D] f32
    const int*   routes = (const int*)d_in[2];     // [N] i32
    const float* rpm    = (const float*)d_in[3];   // [N] f32

    int* srcrow = (int*)d_ws;                      // N_TOK ints = 64 KB scratch

    rank_kernel<<<N_EXP, 64, 0, stream>>>(routes, srcrow);
    combine_kernel<<<NBLK, THREADS, 0, stream>>>(
        (const float4*)hidden, (const float4*)eo, srcrow, rpm, (float4*)d_out);
}

// Round 9
// 74.103 us; speedup vs baseline: 2.0423x; 2.0423x over previous
//
#include <hip/hip_runtime.h>
#include <stdint.h>

// Problem dims (fixed by reference): E=16, B=8, S=2048, D=2048
#define N_TOK   16384          // B*S
#define D_MODEL 2048
#define N_EXP   16
#define CAP     1024           // N_TOK / N_EXP

#define BLK_TOK 8              // token rows per combine block
#define THREADS 256
#define STEPS   16             // float4 groups per thread
#define NBLK    (N_TOK / BLK_TOK)   // 2048 blocks = 8192 waves = 32/CU exactly

// keep  <=>  u < 0.9f  <=>  bits < 7549747<<9  (0.9f == 7549747*2^-23 exactly)
#define KEEP_THR_SH 0xE6666600u

// native 4-float vector for nontemporal builtin (HIP_vector_type is a class)
typedef float nfloat4 __attribute__((ext_vector_type(4)));

// ---------------------------------------------------------------------------
// rotl forced to a single v_alignbit_b32: rotl(x,r) == {x,x} >> (32-r).
// ---------------------------------------------------------------------------
template <int R>
__device__ __forceinline__ uint32_t rotl(uint32_t x) {
    uint32_t d;
    asm("v_alignbit_b32 %0, %1, %1, %2" : "=v"(d) : "v"(x), "n"(32 - R));
    return d;
}

// ---------------------------------------------------------------------------
// Threefry-2x32, 20 rounds, key = (0, 42) == jax.random.key(42).
// Partitionable path: counter = (0, i); 32-bit draw = XOR-fold x0 ^ x1.
// ---------------------------------------------------------------------------
__device__ __forceinline__ uint32_t tf_bits(uint32_t i) {
    const uint32_t k0 = 0u;
    const uint32_t k1 = 42u;
    const uint32_t k2 = 0x1BD11BDAu ^ 0u ^ 42u;
    uint32_t x0 = 0u + k0;        // counter hi = 0
    uint32_t x1 = i + k1;         // counter lo = i
#define TF_R(r) { x0 += x1; x1 = rotl<r>(x1) ^ x0; }
    TF_R(13) TF_R(15) TF_R(26) TF_R(6)
    x0 += k1; x1 += k2 + 1u;
    TF_R(17) TF_R(29) TF_R(16) TF_R(24)
    x0 += k2; x1 += k0 + 2u;
    TF_R(13) TF_R(15) TF_R(26) TF_R(6)
    x0 += k0; x1 += k1 + 3u;
    TF_R(17) TF_R(29) TF_R(16) TF_R(24)
    x0 += k1; x1 += k2 + 4u;
    TF_R(13) TF_R(15) TF_R(26) TF_R(6)
    x0 += k2; x1 += k0 + 5u;
#undef TF_R
    return x0 ^ x1;               // XOR-fold (partitionable sub-64 narrowing)
}

// ---------------------------------------------------------------------------
// Kernel 1: within-expert rank, two-level scan, single pass over routes.
// 16 blocks (one per expert) x 1024 threads (16 waves). Lane owns 16
// CONSECUTIVE tokens (4 int4); wave owns 1024 consecutive tokens; wave
// totals combined via LDS. srcrow[t] = routes[t]*CAP + rank(t).
// ---------------------------------------------------------------------------
__global__ __launch_bounds__(1024) void rank_kernel(const int* __restrict__ routes,
                                                    int* __restrict__ srcrow) {
    const int e    = blockIdx.x;
    const int tid  = threadIdx.x;       // 0..1023
    const int wave = tid >> 6;          // 0..15
    const int lane = tid & 63;
    __shared__ int wave_tot[16];

    const int4* r4 = (const int4*)routes;
    int4 rv[4];
    int  mycnt = 0;
    #pragma unroll
    for (int q = 0; q < 4; ++q) {
        rv[q] = r4[(wave << 8) + (lane << 2) + q];   // 16 consecutive tokens/lane
        mycnt += (rv[q].x == e) + (rv[q].y == e) + (rv[q].z == e) + (rv[q].w == e);
    }

    // inclusive wave scan of mycnt over lanes
    int pre = mycnt;
    #pragma unroll
    for (int d = 1; d < 64; d <<= 1) {
        int up = __shfl_up(pre, d);
        if (lane >= d) pre += up;
    }
    if (lane == 63) wave_tot[wave] = pre;
    __syncthreads();

    int wbase = 0;
    #pragma unroll
    for (int w = 0; w < 16; ++w) wbase += (w < wave) ? wave_tot[w] : 0;

    int p = e * CAP + wbase + (pre - mycnt);   // rank of lane's first match
    #pragma unroll
    for (int q = 0; q < 4; ++q) {
        const int tok = (((wave << 8) + (lane << 2) + q) << 2);
        if (rv[q].x == e) srcrow[tok + 0] = p++;
        if (rv[q].y == e) srcrow[tok + 1] = p++;
        if (rv[q].z == e) srcrow[tok + 2] = p++;
        if (rv[q].w == e) srcrow[tok + 3] = p++;
    }
}

// ---------------------------------------------------------------------------
// Kernel 2: combine + dropout + residual. Long-lived blocks (16 steps),
// 1-deep prefetch pinned with sched_barrier, <=64 VGPR (8 waves/SIMD),
// non-temporal stores for the never-re-read output.
// ---------------------------------------------------------------------------
__global__ __launch_bounds__(THREADS, 8) void combine_kernel(
        const float4* __restrict__ hidden,
        const float4* __restrict__ eo4,
        const int*    __restrict__ srcrow,
        const float*  __restrict__ rpm,
        float4*       __restrict__ out) {
    const int b     = blockIdx.x;
    const int tid   = threadIdx.x;                 // 0..255
    const int t0    = b * BLK_TOK;
    const int gbase = b * (BLK_TOK * 512);         // first float4 of block

    // Block-uniform per-row scalars (scalarize to SGPRs), paid once per block
    int   r[BLK_TOK];
    float sc[BLK_TOK];
    #pragma unroll
    for (int q = 0; q < BLK_TOK; ++q) {
        r[q]  = srcrow[t0 + q];
        sc[q] = rpm[t0 + q] * (1.0f / 0.9f);
    }

    // 1-deep pipeline: loads for step k+1 issue before threefry of step k.
    float4 h = hidden[gbase + tid];
    float4 e = eo4[(r[0] << 9) + tid];

    #pragma unroll
    for (int k = 0; k < STEPS; ++k) {
        float4 hn, en;
        if (k + 1 < STEPS) {
            const int idx = (k + 1) * THREADS + tid;       // within-block f4 idx
            hn = hidden[gbase + idx];
            en = eo4[(r[(k + 1) >> 1] << 9) + (idx & 511)];
        }
        // pin: next-step loads may not sink below; threefry may not hoist above
        __builtin_amdgcn_sched_barrier(0);

        const uint32_t j = (uint32_t)(gbase + k * THREADS + tid) << 2;
        const uint32_t b0 = tf_bits(j + 0);
        const uint32_t b1 = tf_bits(j + 1);
        const uint32_t b2 = tf_bits(j + 2);
        const uint32_t b3 = tf_bits(j + 3);

        const float s  = sc[k >> 1];
        const float m0 = (b0 < KEEP_THR_SH) ? s : 0.0f;
        const float m1 = (b1 < KEEP_THR_SH) ? s : 0.0f;
        const float m2 = (b2 < KEEP_THR_SH) ? s : 0.0f;
        const float m3 = (b3 < KEEP_THR_SH) ? s : 0.0f;

        nfloat4 o;
        o.x = fmaf(m0, e.x, h.x);
        o.y = fmaf(m1, e.y, h.y);
        o.z = fmaf(m2, e.z, h.z);
        o.w = fmaf(m3, e.w, h.w);
        __builtin_nontemporal_store(o, (nfloat4*)&out[gbase + k * THREADS + tid]);

        if (k + 1 < STEPS) { h = hn; e = en; }
    }
}

// ---------------------------------------------------------------------------
extern "C" void kernel_launch(void* const* d_in, const int* in_sizes, int n_in,
                              void* d_out, int out_size, void* d_ws, size_t ws_size,
                              hipStream_t stream) {
    const float* hidden = (const float*)d_in[0];   // [B,S,D] f32
    const float* eo     = (const float*)d_in[1];   // [E,CAP,D] f32
    const int*   routes = (const int*)d_in[2];     // [N] i32
    const float* rpm    = (const float*)d_in[3];   // [N] f32

    int* srcrow = (int*)d_ws;                      // N_TOK ints = 64 KB scratch

    rank_kernel<<<N_EXP, 1024, 0, stream>>>(routes, srcrow);
    combine_kernel<<<NBLK, THREADS, 0, stream>>>(
        (const float4*)hidden, (const float4*)eo, srcrow, rpm, (float4*)d_out);
}